// Round 6
// baseline (518.357 us; speedup 1.0000x reference)
//
#include <hip/hip_runtime.h>
#include <math.h>

// GCN 2-layer forward, MI355X. Round 6: tail-shrink.
//  - k_g1g2: gather1 (+epi) fused with GEMM2 via LDS tile (h2 never global)
//  - k_fine: fused fine CSR (dst) + fine hist (src) + norm computation
//  - k_cscan eliminated (per-block LDS scan of coarse counts)
//  - k_wcvt merged into k_chist (block-range branch)
// 7 dispatches total. Arithmetic path identical to r5 (absmax should match).

#define NF0 256
#define NF1 128
#define NC  47
#define CB  1024   // fine bucket width (nodes per coarse bucket); nbk<=128

typedef __attribute__((ext_vector_type(8))) short bfrag;   // 8 bf16 (4 VGPRs)
typedef __attribute__((ext_vector_type(4))) float f32x4;

__device__ __forceinline__ unsigned short f2bf(float f) {   // RNE
  unsigned u = __float_as_uint(f);
  return (unsigned short)((u + 0x7fffu + ((u >> 16) & 1u)) >> 16);
}
__device__ __forceinline__ unsigned pack2bf(float a, float b) {
  return (unsigned)f2bf(a) | ((unsigned)f2bf(b) << 16);
}
__device__ __forceinline__ float bflo(unsigned v) { return __uint_as_float(v << 16); }
__device__ __forceinline__ float bfhi(unsigned v) { return __uint_as_float(v & 0xffff0000u); }
__device__ __forceinline__ float bf2f(unsigned short b) {
  return __uint_as_float((unsigned)b << 16);
}

// ---------------- threefry2x32 (JAX partitionable path; verified r1/r2) ------------
__device__ __forceinline__ unsigned rotl_(unsigned x, int n) {
  return (x << n) | (x >> (32 - n));
}
__device__ __forceinline__ void threefry2x32_(unsigned x0, unsigned x1,
                                              unsigned& o0, unsigned& o1) {
  const unsigned k0 = 0u, k1 = 42u;
  const unsigned k2 = k0 ^ k1 ^ 0x1BD11BDAu;
  x0 += k0; x1 += k1;
  x0+=x1; x1=rotl_(x1,13); x1^=x0;
  x0+=x1; x1=rotl_(x1,15); x1^=x0;
  x0+=x1; x1=rotl_(x1,26); x1^=x0;
  x0+=x1; x1=rotl_(x1, 6); x1^=x0;
  x0+=k1; x1+=k2+1u;
  x0+=x1; x1=rotl_(x1,17); x1^=x0;
  x0+=x1; x1=rotl_(x1,29); x1^=x0;
  x0+=x1; x1=rotl_(x1,16); x1^=x0;
  x0+=x1; x1=rotl_(x1,24); x1^=x0;
  x0+=k2; x1+=k0+2u;
  x0+=x1; x1=rotl_(x1,13); x1^=x0;
  x0+=x1; x1=rotl_(x1,15); x1^=x0;
  x0+=x1; x1=rotl_(x1,26); x1^=x0;
  x0+=x1; x1=rotl_(x1, 6); x1^=x0;
  x0+=k0; x1+=k1+3u;
  x0+=x1; x1=rotl_(x1,17); x1^=x0;
  x0+=x1; x1=rotl_(x1,29); x1^=x0;
  x0+=x1; x1=rotl_(x1,16); x1^=x0;
  x0+=x1; x1=rotl_(x1,24); x1^=x0;
  x0+=k1; x1+=k2+4u;
  x0+=x1; x1=rotl_(x1,13); x1^=x0;
  x0+=x1; x1=rotl_(x1,15); x1^=x0;
  x0+=x1; x1=rotl_(x1,26); x1^=x0;
  x0+=x1; x1=rotl_(x1, 6); x1^=x0;
  x0+=k2; x1+=k0+5u;
  o0 = x0; o1 = x1;
}
__device__ __forceinline__ float dropout_mul(int j) {
  unsigned o0, o1;
  threefry2x32_(0u, (unsigned)j, o0, o1);
  unsigned bits = o0 ^ o1;
  float u = __uint_as_float((bits >> 9) | 0x3f800000u) - 1.0f;
  return (u < 0.8f) ? 1.25f : 0.0f;
}

// ================= preprocessing =================

// P1: coarse histogram (blocks 0..255) + weight convert (blocks >=256).
// W1t32[n][kp]: packed bf16 pair of W1[2kp..2kp+1][n]  (128x128 uints)
// W2t32[f][kp]: packed bf16 pair of W2[2kp..2kp+1][f], f>=47 -> 0 (48x64 uints)
__global__ __launch_bounds__(256) void k_chist(const int* __restrict__ ei, int E,
                                               int nbk,
                                               unsigned* __restrict__ bCntD,
                                               unsigned* __restrict__ bCntS,
                                               const float* __restrict__ W1,
                                               const float* __restrict__ W2,
                                               unsigned* __restrict__ W1t32,
                                               unsigned* __restrict__ W2t32) {
  if (blockIdx.x >= 256) {
    int i = (blockIdx.x - 256) * 256 + threadIdx.x;
    if (i < 128 * 128) {
      int n = i >> 7, k = (i & 127) << 1;
      W1t32[i] = pack2bf(W1[(size_t)k * NF1 + n], W1[(size_t)(k + 1) * NF1 + n]);
    } else if (i < 128 * 128 + 48 * 64) {
      int j = i - 128 * 128;
      int f = j >> 6, k = (j & 63) << 1;
      float a = (f < NC) ? W2[(size_t)k * NC + f] : 0.f;
      float c = (f < NC) ? W2[(size_t)(k + 1) * NC + f] : 0.f;
      W2t32[j] = pack2bf(a, c);
    }
    return;
  }
  __shared__ unsigned hd[128], hs[128];
  for (int i = threadIdx.x; i < 128; i += 256) { hd[i] = 0; hs[i] = 0; }
  __syncthreads();
  for (int e = blockIdx.x * 256 + threadIdx.x; e < E; e += 256 * 256) {
    int s = ei[e], d = ei[E + e];
    atomicAdd(&hs[s >> 10], 1u);
    atomicAdd(&hd[d >> 10], 1u);
  }
  __syncthreads();
  for (int i = threadIdx.x; i < nbk; i += 256) {
    if (hd[i]) atomicAdd(&bCntD[i], hd[i]);
    if (hs[i]) atomicAdd(&bCntS[i], hs[i]);
  }
}

// P2: coarse scatter. Coarse offsets derived per-block by a 128-wide LDS scan
// of bCntD/bCntS (both halves in one 256-wide scan); chunk reservation on
// zero-initialized cursors. pd=(dstLocal<<17)|src; ps=srcLocal.
__global__ __launch_bounds__(256) void k_cscatter(const int* __restrict__ ei, int E,
                                                  const unsigned* __restrict__ bCntD,
                                                  const unsigned* __restrict__ bCntS,
                                                  unsigned* __restrict__ curD,
                                                  unsigned* __restrict__ curS,
                                                  unsigned* __restrict__ pd,
                                                  unsigned short* __restrict__ ps,
                                                  int nbk) {
  __shared__ unsigned hd[128], hs[128];
  __shared__ unsigned baseD[128], baseS[128];
  __shared__ unsigned sc[256];
  const int t = threadIdx.x;
  int per = (E + gridDim.x - 1) / gridDim.x;
  int e0 = blockIdx.x * per;
  int e1 = min(e0 + per, E);
  unsigned orig = (t < 128) ? ((t < nbk) ? bCntD[t] : 0u)
                            : (((t - 128) < nbk) ? bCntS[t - 128] : 0u);
  sc[t] = orig;
  if (t < 128) { hd[t] = 0; hs[t] = 0; }
  __syncthreads();
  for (int e = e0 + t; e < e1; e += 256) {
    int s = ei[e], d = ei[E + e];
    atomicAdd(&hs[s >> 10], 1u);
    atomicAdd(&hd[d >> 10], 1u);
  }
  __syncthreads();
  #pragma unroll
  for (int o = 1; o < 128; o <<= 1) {
    unsigned u = ((t & 127) >= o) ? sc[t - o] : 0u;
    __syncthreads();
    sc[t] += u;
    __syncthreads();
  }
  if (t < 128) {
    unsigned excl = sc[t] - orig;
    unsigned h = hd[t];
    baseD[t] = excl + (h ? atomicAdd(&curD[t], h) : 0u);
    hd[t] = 0;
  } else {
    int i = t - 128;
    unsigned excl = sc[t] - orig;
    unsigned h = hs[i];
    baseS[i] = excl + (h ? atomicAdd(&curS[i], h) : 0u);
    hs[i] = 0;
  }
  __syncthreads();
  for (int e = e0 + t; e < e1; e += 256) {
    int s = ei[e], d = ei[E + e];
    int bd = d >> 10, bs = s >> 10;
    unsigned pD = baseD[bd] + atomicAdd(&hd[bd], 1u);
    unsigned pS = baseS[bs] + atomicAdd(&hs[bs], 1u);
    pd[pD] = ((unsigned)(d & (CB - 1)) << 17) | (unsigned)s;
    ps[pS] = (unsigned short)(s & (CB - 1));
  }
}

// P3: fused fine pass, grid = 2*nbk.
//  blocks [0,nbk):   dst buckets -> off, norm_dst, dst-sorted csr
//  blocks [nbk,2nbk): src buckets -> norm_src
__global__ __launch_bounds__(256) void k_fine(const unsigned* __restrict__ bCntD,
                                              const unsigned* __restrict__ bCntS,
                                              const unsigned* __restrict__ pd,
                                              const unsigned short* __restrict__ ps,
                                              unsigned* __restrict__ off,
                                              float* __restrict__ norm_dst,
                                              float* __restrict__ norm_src,
                                              int* __restrict__ csr,
                                              int N, int E, int nbk) {
  __shared__ unsigned cnt[CB];
  __shared__ unsigned part[256];
  __shared__ unsigned sc[256];
  const int t = threadIdx.x;
  const bool isD = (int)blockIdx.x < nbk;
  const int b = isD ? (int)blockIdx.x : ((int)blockIdx.x - nbk);
  unsigned orig = (t < 128) ? ((t < nbk) ? bCntD[t] : 0u)
                            : (((t - 128) < nbk) ? bCntS[t - 128] : 0u);
  sc[t] = orig;
  __syncthreads();
  #pragma unroll
  for (int o = 1; o < 128; o <<= 1) {
    unsigned u = ((t & 127) >= o) ? sc[t - o] : 0u;
    __syncthreads();
    sc[t] += u;
    __syncthreads();
  }
  const int idx = isD ? b : (128 + b);
  const unsigned hi = sc[idx];
  const unsigned lo = hi - (isD ? bCntD[b] : bCntS[b]);
  const int base = b << 10;
  for (int i = t; i < CB; i += 256) cnt[i] = 0;
  __syncthreads();
  if (isD) {
    for (unsigned j = lo + t; j < hi; j += 256) atomicAdd(&cnt[pd[j] >> 17], 1u);
    __syncthreads();
    unsigned c0 = cnt[4*t], c1 = cnt[4*t+1], c2 = cnt[4*t+2], c3 = cnt[4*t+3];
    unsigned tsum = c0 + c1 + c2 + c3;
    part[t] = tsum;
    __syncthreads();
    #pragma unroll
    for (int o = 1; o < 256; o <<= 1) {
      unsigned u = (t >= o) ? part[t - o] : 0u;
      __syncthreads();
      part[t] += u;
      __syncthreads();
    }
    unsigned e0 = part[t] - tsum;
    unsigned p0 = e0, p1 = e0 + c0, p2 = p1 + c1, p3 = p2 + c2;
    int n0 = base + 4 * t;
    if (n0 + 0 < N) { off[n0+0] = lo + p0; norm_dst[n0+0] = 1.0f / sqrtf((float)(c0 < 1u ? 1u : c0)); }
    if (n0 + 1 < N) { off[n0+1] = lo + p1; norm_dst[n0+1] = 1.0f / sqrtf((float)(c1 < 1u ? 1u : c1)); }
    if (n0 + 2 < N) { off[n0+2] = lo + p2; norm_dst[n0+2] = 1.0f / sqrtf((float)(c2 < 1u ? 1u : c2)); }
    if (n0 + 3 < N) { off[n0+3] = lo + p3; norm_dst[n0+3] = 1.0f / sqrtf((float)(c3 < 1u ? 1u : c3)); }
    if (b == nbk - 1 && t == 0) off[N] = (unsigned)E;
    __syncthreads();
    cnt[4*t] = p0; cnt[4*t+1] = p1; cnt[4*t+2] = p2; cnt[4*t+3] = p3;   // cursors
    __syncthreads();
    for (unsigned j = lo + t; j < hi; j += 256) {
      unsigned v = pd[j];
      unsigned pos = atomicAdd(&cnt[v >> 17], 1u);
      csr[lo + pos] = (int)(v & 0x1FFFFu);
    }
  } else {
    for (unsigned j = lo + t; j < hi; j += 256) atomicAdd(&cnt[ps[j]], 1u);
    __syncthreads();
    for (int i = t; i < CB; i += 256) {
      int n = base + i;
      if (n < N) {
        unsigned c = cnt[i];
        norm_src[n] = 1.0f / sqrtf((float)(c < 1u ? 1u : c));
      }
    }
  }
}

// ---------------- GEMM1 (MFMA bf16): h1[m,n] = ns[m] * sum_k x[m,k] W1[k,n] --------
__global__ __launch_bounds__(256) void k_gemm1(const float* __restrict__ x,
                                               const unsigned* __restrict__ W1t32,
                                               const float* __restrict__ norm_src,
                                               unsigned short* __restrict__ h1, int N) {
  __shared__ unsigned As[128][20];   // 16 used + 4 pad
  __shared__ unsigned Bs[128][20];
  const int m0 = blockIdx.x * 128;
  const int t = threadIdx.x;
  const int lane = t & 63, wid = t >> 6;
  const int fr = lane & 15, ko = (lane >> 4) * 8;

  f32x4 acc[2][8];
  #pragma unroll
  for (int r = 0; r < 2; r++)
    #pragma unroll
    for (int c = 0; c < 8; c++) acc[r][c] = (f32x4){0.f, 0.f, 0.f, 0.f};

  const int sr = t >> 1;
  const int shw = (t & 1) * 8;

  for (int k0 = 0; k0 < NF0; k0 += 32) {
    {
      unsigned w[8];
      int gm = m0 + sr;
      if (gm < N) {
        const float* p = x + (size_t)gm * NF0 + k0 + shw * 2;
        #pragma unroll
        for (int q = 0; q < 4; q++) {
          float4 v = *(const float4*)(p + q * 4);
          w[2*q]   = pack2bf(v.x, v.y);
          w[2*q+1] = pack2bf(v.z, v.w);
        }
      } else {
        #pragma unroll
        for (int q = 0; q < 8; q++) w[q] = 0u;
      }
      *(uint4*)&As[sr][shw]     = make_uint4(w[0], w[1], w[2], w[3]);
      *(uint4*)&As[sr][shw + 4] = make_uint4(w[4], w[5], w[6], w[7]);
    }
    {
      const unsigned* pb = W1t32 + (size_t)sr * (NF0 / 2) + (k0 >> 1) + shw;
      *(uint4*)&Bs[sr][shw]     = *(const uint4*)pb;
      *(uint4*)&Bs[sr][shw + 4] = *(const uint4*)(pb + 4);
    }
    __syncthreads();
    const unsigned short* As16 = (const unsigned short*)&As[0][0];
    const unsigned short* Bs16 = (const unsigned short*)&Bs[0][0];
    #pragma unroll
    for (int r = 0; r < 2; r++) {
      bfrag a = *(const bfrag*)(As16 + (size_t)(wid * 32 + r * 16 + fr) * 40 + ko);
      #pragma unroll
      for (int c = 0; c < 8; c++) {
        bfrag b = *(const bfrag*)(Bs16 + (size_t)(c * 16 + fr) * 40 + ko);
        acc[r][c] = __builtin_amdgcn_mfma_f32_16x16x32_bf16(a, b, acc[r][c], 0, 0, 0);
      }
    }
    __syncthreads();
  }

  #pragma unroll
  for (int r = 0; r < 2; r++) {
    int rbase = m0 + wid * 32 + r * 16 + (lane >> 4) * 4;
    float ns[4];
    #pragma unroll
    for (int g = 0; g < 4; g++) ns[g] = (rbase + g < N) ? norm_src[rbase + g] : 0.f;
    #pragma unroll
    for (int c = 0; c < 8; c++) {
      int col = c * 16 + fr;
      #pragma unroll
      for (int g = 0; g < 4; g++) {
        int row = rbase + g;
        if (row < N) h1[(size_t)row * NF1 + col] = f2bf(acc[r][c][g] * ns[g]);
      }
    }
  }
}

// ---------------- fused gather1 + GEMM2 ----------------
// Block = 64 dst nodes. Phase A: 4 waves gather h2 rows (dropout/relu/norm
// fused) into LDS bf16 tile. Phase B: GEMM2 tile from LDS + W2 (global, hot)
// -> g (bf16, stride 48).
#define G2PAD 70   // uint stride per tile row (140 ushorts; 4-way LDS aliasing max)
__global__ __launch_bounds__(256) void k_g1g2(const unsigned* __restrict__ off,
                                              const int* __restrict__ csr,
                                              const unsigned short* __restrict__ h1,
                                              const float* __restrict__ norm_dst,
                                              const float* __restrict__ norm_src,
                                              const float* __restrict__ b1,
                                              const unsigned* __restrict__ W2t32,
                                              unsigned short* __restrict__ g, int N) {
  __shared__ unsigned hsb[64 * G2PAD];
  const int t = threadIdx.x;
  const int m0 = blockIdx.x * 64;
  const int lane = t & 63, wid = t >> 6;
  const int f = lane << 1;

  for (int nn = 0; nn < 16; nn++) {
    int lrow = wid * 16 + nn;
    int node = m0 + lrow;
    if (node >= N) break;
    unsigned j = off[node], e1 = off[node + 1];
    float ax = 0.f, ay = 0.f;
    for (; j + 4 <= e1; j += 4) {
      int s0 = csr[j], s1 = csr[j+1], s2 = csr[j+2], s3 = csr[j+3];
      unsigned v0 = *(const unsigned*)(h1 + (size_t)s0 * NF1 + f);
      unsigned v1 = *(const unsigned*)(h1 + (size_t)s1 * NF1 + f);
      unsigned v2 = *(const unsigned*)(h1 + (size_t)s2 * NF1 + f);
      unsigned v3 = *(const unsigned*)(h1 + (size_t)s3 * NF1 + f);
      ax += (bflo(v0) + bflo(v1)) + (bflo(v2) + bflo(v3));
      ay += (bfhi(v0) + bfhi(v1)) + (bfhi(v2) + bfhi(v3));
    }
    for (; j < e1; j++) {
      unsigned v = *(const unsigned*)(h1 + (size_t)csr[j] * NF1 + f);
      ax += bflo(v); ay += bfhi(v);
    }
    float nd = norm_dst[node], ns = norm_src[node];
    float2 bb = *(const float2*)(b1 + f);
    float v0 = fmaxf(ax * nd + bb.x, 0.f);
    float v1 = fmaxf(ay * nd + bb.y, 0.f);
    int jf = node * NF1 + f;
    v0 *= dropout_mul(jf) * ns;
    v1 *= dropout_mul(jf + 1) * ns;
    hsb[lrow * G2PAD + lane] = pack2bf(v0, v1);
  }
  __syncthreads();

  const int fg = t & 15, mg = t >> 4;
  const int f0 = fg * 3, mt = mg * 4;
  float acc[4][3] = {{0.f}};
  for (int k = 0; k < NF1; k += 4) {
    float a[4][4];
    #pragma unroll
    for (int i = 0; i < 4; i++) {
      uint2 u = *(const uint2*)&hsb[(mt + i) * G2PAD + (k >> 1)];
      a[i][0] = bflo(u.x); a[i][1] = bfhi(u.x);
      a[i][2] = bflo(u.y); a[i][3] = bfhi(u.y);
    }
    float bv[3][4];
    #pragma unroll
    for (int jj = 0; jj < 3; jj++) {
      uint2 u = *(const uint2*)(W2t32 + (size_t)(f0 + jj) * 64 + (k >> 1));
      bv[jj][0] = bflo(u.x); bv[jj][1] = bfhi(u.x);
      bv[jj][2] = bflo(u.y); bv[jj][3] = bfhi(u.y);
    }
    #pragma unroll
    for (int i = 0; i < 4; i++)
      #pragma unroll
      for (int jj = 0; jj < 3; jj++)
        acc[i][jj] += a[i][0]*bv[jj][0] + a[i][1]*bv[jj][1]
                    + a[i][2]*bv[jj][2] + a[i][3]*bv[jj][3];
  }
  #pragma unroll
  for (int i = 0; i < 4; i++) {
    int gm = m0 + mt + i;
    if (gm < N) {
      #pragma unroll
      for (int jj = 0; jj < 3; jj++)
        g[(size_t)gm * 48 + f0 + jj] = f2bf(acc[i][jj]);
    }
  }
}

// ---------------- gather2 + bias + log_softmax -> out ----------------
__global__ __launch_bounds__(256) void k_gather2(const unsigned* __restrict__ off,
                                                 const int* __restrict__ csr,
                                                 const unsigned short* __restrict__ g,
                                                 const float* __restrict__ norm_dst,
                                                 const float* __restrict__ b2,
                                                 float* __restrict__ out, int N) {
  int node = (blockIdx.x * 256 + threadIdx.x) >> 6;
  int lane = threadIdx.x & 63;
  if (node >= N) return;
  unsigned j = off[node], e1 = off[node + 1];
  float acc = 0.f;
  for (; j + 4 <= e1; j += 4) {
    int s0 = csr[j], s1 = csr[j+1], s2 = csr[j+2], s3 = csr[j+3];
    if (lane < 48) {
      float a0 = bf2f(g[(size_t)s0 * 48 + lane]);
      float a1 = bf2f(g[(size_t)s1 * 48 + lane]);
      float a2 = bf2f(g[(size_t)s2 * 48 + lane]);
      float a3 = bf2f(g[(size_t)s3 * 48 + lane]);
      acc += (a0 + a1) + (a2 + a3);
    }
  }
  for (; j < e1; j++) {
    if (lane < 48) acc += bf2f(g[(size_t)csr[j] * 48 + lane]);
  }
  float nd = norm_dst[node];
  float vr = 0.f, m = -INFINITY;
  if (lane < NC) {
    vr = acc * nd + b2[lane];
    m = vr;
  }
  #pragma unroll
  for (int o = 32; o; o >>= 1) m = fmaxf(m, __shfl_xor(m, o));
  float ex = (lane < NC) ? expf(vr - m) : 0.f;
  #pragma unroll
  for (int o = 32; o; o >>= 1) ex += __shfl_xor(ex, o);
  float ls = logf(ex);
  if (lane < NC) out[(size_t)node * NC + lane] = vr - m - ls;
}

extern "C" void kernel_launch(void* const* d_in, const int* in_sizes, int n_in,
                              void* d_out, int out_size, void* d_ws, size_t ws_size,
                              hipStream_t stream) {
  const float* x  = (const float*)d_in[0];
  const int*   ei = (const int*)d_in[1];
  const float* W1 = (const float*)d_in[2];
  const float* b1 = (const float*)d_in[3];
  const float* W2 = (const float*)d_in[4];
  const float* b2 = (const float*)d_in[5];
  float* out = (float*)d_out;

  const int N = in_sizes[0] / NF0;   // 100000
  const int E = in_sizes[1] / 2;     // 1600000
  const int nbk = (N + CB - 1) / CB; // 98

  unsigned* ws = (unsigned*)d_ws;
  size_t o = 0;
  auto alloc = [&](size_t elems) { size_t p = o; o += (elems + 3) & ~(size_t)3; return p; };
  float*    norm_src = (float*)(ws + alloc(N));
  float*    norm_dst = (float*)(ws + alloc(N));
  unsigned* off      = ws + alloc(N + 1);
  unsigned* bCntD    = ws + alloc(128);   // bCntD,bCntS,curD,curS contiguous: one memset
  unsigned* bCntS    = ws + alloc(128);
  unsigned* curD     = ws + alloc(128);
  unsigned* curS     = ws + alloc(128);
  unsigned* pd       = ws + alloc(E);                        // 6.4 MB
  unsigned short* ps = (unsigned short*)(ws + alloc(E / 2)); // 3.2 MB
  int*      csr      = (int*)(ws + alloc(E));                // 6.4 MB
  unsigned* W1t32    = ws + alloc(128 * 128);
  unsigned* W2t32    = ws + alloc(48 * 64);
  unsigned short* h1 = (unsigned short*)(ws + alloc((size_t)N * NF1 / 2));
  // g (N*48 bf16) overlays pd+ps (dead after k_fine): E*3 ushorts available.
  unsigned short* gbuf;
  if ((size_t)E * 3 >= (size_t)N * 48) {
    gbuf = (unsigned short*)pd;
  } else {
    gbuf = (unsigned short*)(ws + alloc(((size_t)N * 48 + 1) / 2));
  }

  hipMemsetAsync(bCntD, 0, 512 * sizeof(unsigned), stream);

  int wblk = (128 * 128 + 48 * 64 + 255) / 256;
  k_chist<<<256 + wblk, 256, 0, stream>>>(ei, E, nbk, bCntD, bCntS, W1, W2, W1t32, W2t32);
  k_cscatter<<<256, 256, 0, stream>>>(ei, E, bCntD, bCntS, curD, curS, pd, ps, nbk);
  k_fine<<<2 * nbk, 256, 0, stream>>>(bCntD, bCntS, pd, ps, off, norm_dst, norm_src,
                                      csr, N, E, nbk);
  k_gemm1<<<(N + 127) / 128, 256, 0, stream>>>(x, W1t32, norm_src, h1, N);
  k_g1g2<<<(N + 63) / 64, 256, 0, stream>>>(off, csr, h1, norm_dst, norm_src, b1,
                                            W2t32, gbuf, N);
  k_gather2<<<((size_t)N * 64 + 255) / 256, 256, 0, stream>>>(
      off, csr, gbuf, norm_dst, b2, out, N);
}

// Round 7
// 495.586 us; speedup vs baseline: 1.0459x; 1.0459x over previous
//
#include <hip/hip_runtime.h>
#include <math.h>

// GCN 2-layer forward, MI355X. Round 7: r6 preprocessing + wave-per-node
// fused gather1+gemm2 (k_g1g2 v2). One wave gathers one node (full latency
// parallelism, like r5's 91us gather1), then computes that node's 47 layer-2
// outputs in-wave via an LDS-staged W2 tile (grid-stride persistent blocks
// amortize the staging). h2 never touches global memory.

#define NF0 256
#define NF1 128
#define NC  47
#define CB  1024   // fine bucket width (nodes per coarse bucket); nbk<=128

typedef __attribute__((ext_vector_type(8))) short bfrag;   // 8 bf16 (4 VGPRs)
typedef __attribute__((ext_vector_type(4))) float f32x4;

__device__ __forceinline__ unsigned short f2bf(float f) {   // RNE
  unsigned u = __float_as_uint(f);
  return (unsigned short)((u + 0x7fffu + ((u >> 16) & 1u)) >> 16);
}
__device__ __forceinline__ unsigned pack2bf(float a, float b) {
  return (unsigned)f2bf(a) | ((unsigned)f2bf(b) << 16);
}
__device__ __forceinline__ float bflo(unsigned v) { return __uint_as_float(v << 16); }
__device__ __forceinline__ float bfhi(unsigned v) { return __uint_as_float(v & 0xffff0000u); }
__device__ __forceinline__ float bf2f(unsigned short b) {
  return __uint_as_float((unsigned)b << 16);
}

// ---------------- threefry2x32 (JAX partitionable path; verified r1/r2) ------------
__device__ __forceinline__ unsigned rotl_(unsigned x, int n) {
  return (x << n) | (x >> (32 - n));
}
__device__ __forceinline__ void threefry2x32_(unsigned x0, unsigned x1,
                                              unsigned& o0, unsigned& o1) {
  const unsigned k0 = 0u, k1 = 42u;
  const unsigned k2 = k0 ^ k1 ^ 0x1BD11BDAu;
  x0 += k0; x1 += k1;
  x0+=x1; x1=rotl_(x1,13); x1^=x0;
  x0+=x1; x1=rotl_(x1,15); x1^=x0;
  x0+=x1; x1=rotl_(x1,26); x1^=x0;
  x0+=x1; x1=rotl_(x1, 6); x1^=x0;
  x0+=k1; x1+=k2+1u;
  x0+=x1; x1=rotl_(x1,17); x1^=x0;
  x0+=x1; x1=rotl_(x1,29); x1^=x0;
  x0+=x1; x1=rotl_(x1,16); x1^=x0;
  x0+=x1; x1=rotl_(x1,24); x1^=x0;
  x0+=k2; x1+=k0+2u;
  x0+=x1; x1=rotl_(x1,13); x1^=x0;
  x0+=x1; x1=rotl_(x1,15); x1^=x0;
  x0+=x1; x1=rotl_(x1,26); x1^=x0;
  x0+=x1; x1=rotl_(x1, 6); x1^=x0;
  x0+=k0; x1+=k1+3u;
  x0+=x1; x1=rotl_(x1,17); x1^=x0;
  x0+=x1; x1=rotl_(x1,29); x1^=x0;
  x0+=x1; x1=rotl_(x1,16); x1^=x0;
  x0+=x1; x1=rotl_(x1,24); x1^=x0;
  x0+=k1; x1+=k2+4u;
  x0+=x1; x1=rotl_(x1,13); x1^=x0;
  x0+=x1; x1=rotl_(x1,15); x1^=x0;
  x0+=x1; x1=rotl_(x1,26); x1^=x0;
  x0+=x1; x1=rotl_(x1, 6); x1^=x0;
  x0+=k2; x1+=k0+5u;
  o0 = x0; o1 = x1;
}
__device__ __forceinline__ float dropout_mul(int j) {
  unsigned o0, o1;
  threefry2x32_(0u, (unsigned)j, o0, o1);
  unsigned bits = o0 ^ o1;
  float u = __uint_as_float((bits >> 9) | 0x3f800000u) - 1.0f;
  return (u < 0.8f) ? 1.25f : 0.0f;
}

// ================= preprocessing (unchanged from r6) =================

// P1: coarse histogram (blocks 0..255) + weight convert (blocks >=256).
__global__ __launch_bounds__(256) void k_chist(const int* __restrict__ ei, int E,
                                               int nbk,
                                               unsigned* __restrict__ bCntD,
                                               unsigned* __restrict__ bCntS,
                                               const float* __restrict__ W1,
                                               const float* __restrict__ W2,
                                               unsigned* __restrict__ W1t32,
                                               unsigned* __restrict__ W2t32) {
  if (blockIdx.x >= 256) {
    int i = (blockIdx.x - 256) * 256 + threadIdx.x;
    if (i < 128 * 128) {
      int n = i >> 7, k = (i & 127) << 1;
      W1t32[i] = pack2bf(W1[(size_t)k * NF1 + n], W1[(size_t)(k + 1) * NF1 + n]);
    } else if (i < 128 * 128 + 48 * 64) {
      int j = i - 128 * 128;
      int f = j >> 6, k = (j & 63) << 1;
      float a = (f < NC) ? W2[(size_t)k * NC + f] : 0.f;
      float c = (f < NC) ? W2[(size_t)(k + 1) * NC + f] : 0.f;
      W2t32[j] = pack2bf(a, c);
    }
    return;
  }
  __shared__ unsigned hd[128], hs[128];
  for (int i = threadIdx.x; i < 128; i += 256) { hd[i] = 0; hs[i] = 0; }
  __syncthreads();
  for (int e = blockIdx.x * 256 + threadIdx.x; e < E; e += 256 * 256) {
    int s = ei[e], d = ei[E + e];
    atomicAdd(&hs[s >> 10], 1u);
    atomicAdd(&hd[d >> 10], 1u);
  }
  __syncthreads();
  for (int i = threadIdx.x; i < nbk; i += 256) {
    if (hd[i]) atomicAdd(&bCntD[i], hd[i]);
    if (hs[i]) atomicAdd(&bCntS[i], hs[i]);
  }
}

// P2: coarse scatter with per-block LDS scan of coarse counts + chunk reservation.
__global__ __launch_bounds__(256) void k_cscatter(const int* __restrict__ ei, int E,
                                                  const unsigned* __restrict__ bCntD,
                                                  const unsigned* __restrict__ bCntS,
                                                  unsigned* __restrict__ curD,
                                                  unsigned* __restrict__ curS,
                                                  unsigned* __restrict__ pd,
                                                  unsigned short* __restrict__ ps,
                                                  int nbk) {
  __shared__ unsigned hd[128], hs[128];
  __shared__ unsigned baseD[128], baseS[128];
  __shared__ unsigned sc[256];
  const int t = threadIdx.x;
  int per = (E + gridDim.x - 1) / gridDim.x;
  int e0 = blockIdx.x * per;
  int e1 = min(e0 + per, E);
  unsigned orig = (t < 128) ? ((t < nbk) ? bCntD[t] : 0u)
                            : (((t - 128) < nbk) ? bCntS[t - 128] : 0u);
  sc[t] = orig;
  if (t < 128) { hd[t] = 0; hs[t] = 0; }
  __syncthreads();
  for (int e = e0 + t; e < e1; e += 256) {
    int s = ei[e], d = ei[E + e];
    atomicAdd(&hs[s >> 10], 1u);
    atomicAdd(&hd[d >> 10], 1u);
  }
  __syncthreads();
  #pragma unroll
  for (int o = 1; o < 128; o <<= 1) {
    unsigned u = ((t & 127) >= o) ? sc[t - o] : 0u;
    __syncthreads();
    sc[t] += u;
    __syncthreads();
  }
  if (t < 128) {
    unsigned excl = sc[t] - orig;
    unsigned h = hd[t];
    baseD[t] = excl + (h ? atomicAdd(&curD[t], h) : 0u);
    hd[t] = 0;
  } else {
    int i = t - 128;
    unsigned excl = sc[t] - orig;
    unsigned h = hs[i];
    baseS[i] = excl + (h ? atomicAdd(&curS[i], h) : 0u);
    hs[i] = 0;
  }
  __syncthreads();
  for (int e = e0 + t; e < e1; e += 256) {
    int s = ei[e], d = ei[E + e];
    int bd = d >> 10, bs = s >> 10;
    unsigned pD = baseD[bd] + atomicAdd(&hd[bd], 1u);
    unsigned pS = baseS[bs] + atomicAdd(&hs[bs], 1u);
    pd[pD] = ((unsigned)(d & (CB - 1)) << 17) | (unsigned)s;
    ps[pS] = (unsigned short)(s & (CB - 1));
  }
}

// P3: fused fine pass, grid = 2*nbk (dst: off/norm_dst/csr; src: norm_src).
__global__ __launch_bounds__(256) void k_fine(const unsigned* __restrict__ bCntD,
                                              const unsigned* __restrict__ bCntS,
                                              const unsigned* __restrict__ pd,
                                              const unsigned short* __restrict__ ps,
                                              unsigned* __restrict__ off,
                                              float* __restrict__ norm_dst,
                                              float* __restrict__ norm_src,
                                              int* __restrict__ csr,
                                              int N, int E, int nbk) {
  __shared__ unsigned cnt[CB];
  __shared__ unsigned part[256];
  __shared__ unsigned sc[256];
  const int t = threadIdx.x;
  const bool isD = (int)blockIdx.x < nbk;
  const int b = isD ? (int)blockIdx.x : ((int)blockIdx.x - nbk);
  unsigned orig = (t < 128) ? ((t < nbk) ? bCntD[t] : 0u)
                            : (((t - 128) < nbk) ? bCntS[t - 128] : 0u);
  sc[t] = orig;
  __syncthreads();
  #pragma unroll
  for (int o = 1; o < 128; o <<= 1) {
    unsigned u = ((t & 127) >= o) ? sc[t - o] : 0u;
    __syncthreads();
    sc[t] += u;
    __syncthreads();
  }
  const int idx = isD ? b : (128 + b);
  const unsigned hi = sc[idx];
  const unsigned lo = hi - (isD ? bCntD[b] : bCntS[b]);
  const int base = b << 10;
  for (int i = t; i < CB; i += 256) cnt[i] = 0;
  __syncthreads();
  if (isD) {
    for (unsigned j = lo + t; j < hi; j += 256) atomicAdd(&cnt[pd[j] >> 17], 1u);
    __syncthreads();
    unsigned c0 = cnt[4*t], c1 = cnt[4*t+1], c2 = cnt[4*t+2], c3 = cnt[4*t+3];
    unsigned tsum = c0 + c1 + c2 + c3;
    part[t] = tsum;
    __syncthreads();
    #pragma unroll
    for (int o = 1; o < 256; o <<= 1) {
      unsigned u = (t >= o) ? part[t - o] : 0u;
      __syncthreads();
      part[t] += u;
      __syncthreads();
    }
    unsigned e0 = part[t] - tsum;
    unsigned p0 = e0, p1 = e0 + c0, p2 = p1 + c1, p3 = p2 + c2;
    int n0 = base + 4 * t;
    if (n0 + 0 < N) { off[n0+0] = lo + p0; norm_dst[n0+0] = 1.0f / sqrtf((float)(c0 < 1u ? 1u : c0)); }
    if (n0 + 1 < N) { off[n0+1] = lo + p1; norm_dst[n0+1] = 1.0f / sqrtf((float)(c1 < 1u ? 1u : c1)); }
    if (n0 + 2 < N) { off[n0+2] = lo + p2; norm_dst[n0+2] = 1.0f / sqrtf((float)(c2 < 1u ? 1u : c2)); }
    if (n0 + 3 < N) { off[n0+3] = lo + p3; norm_dst[n0+3] = 1.0f / sqrtf((float)(c3 < 1u ? 1u : c3)); }
    if (b == nbk - 1 && t == 0) off[N] = (unsigned)E;
    __syncthreads();
    cnt[4*t] = p0; cnt[4*t+1] = p1; cnt[4*t+2] = p2; cnt[4*t+3] = p3;   // cursors
    __syncthreads();
    for (unsigned j = lo + t; j < hi; j += 256) {
      unsigned v = pd[j];
      unsigned pos = atomicAdd(&cnt[v >> 17], 1u);
      csr[lo + pos] = (int)(v & 0x1FFFFu);
    }
  } else {
    for (unsigned j = lo + t; j < hi; j += 256) atomicAdd(&cnt[ps[j]], 1u);
    __syncthreads();
    for (int i = t; i < CB; i += 256) {
      int n = base + i;
      if (n < N) {
        unsigned c = cnt[i];
        norm_src[n] = 1.0f / sqrtf((float)(c < 1u ? 1u : c));
      }
    }
  }
}

// ---------------- GEMM1 (MFMA bf16): h1[m,n] = ns[m] * sum_k x[m,k] W1[k,n] --------
__global__ __launch_bounds__(256) void k_gemm1(const float* __restrict__ x,
                                               const unsigned* __restrict__ W1t32,
                                               const float* __restrict__ norm_src,
                                               unsigned short* __restrict__ h1, int N) {
  __shared__ unsigned As[128][20];   // 16 used + 4 pad
  __shared__ unsigned Bs[128][20];
  const int m0 = blockIdx.x * 128;
  const int t = threadIdx.x;
  const int lane = t & 63, wid = t >> 6;
  const int fr = lane & 15, ko = (lane >> 4) * 8;

  f32x4 acc[2][8];
  #pragma unroll
  for (int r = 0; r < 2; r++)
    #pragma unroll
    for (int c = 0; c < 8; c++) acc[r][c] = (f32x4){0.f, 0.f, 0.f, 0.f};

  const int sr = t >> 1;
  const int shw = (t & 1) * 8;

  for (int k0 = 0; k0 < NF0; k0 += 32) {
    {
      unsigned w[8];
      int gm = m0 + sr;
      if (gm < N) {
        const float* p = x + (size_t)gm * NF0 + k0 + shw * 2;
        #pragma unroll
        for (int q = 0; q < 4; q++) {
          float4 v = *(const float4*)(p + q * 4);
          w[2*q]   = pack2bf(v.x, v.y);
          w[2*q+1] = pack2bf(v.z, v.w);
        }
      } else {
        #pragma unroll
        for (int q = 0; q < 8; q++) w[q] = 0u;
      }
      *(uint4*)&As[sr][shw]     = make_uint4(w[0], w[1], w[2], w[3]);
      *(uint4*)&As[sr][shw + 4] = make_uint4(w[4], w[5], w[6], w[7]);
    }
    {
      const unsigned* pb = W1t32 + (size_t)sr * (NF0 / 2) + (k0 >> 1) + shw;
      *(uint4*)&Bs[sr][shw]     = *(const uint4*)pb;
      *(uint4*)&Bs[sr][shw + 4] = *(const uint4*)(pb + 4);
    }
    __syncthreads();
    const unsigned short* As16 = (const unsigned short*)&As[0][0];
    const unsigned short* Bs16 = (const unsigned short*)&Bs[0][0];
    #pragma unroll
    for (int r = 0; r < 2; r++) {
      bfrag a = *(const bfrag*)(As16 + (size_t)(wid * 32 + r * 16 + fr) * 40 + ko);
      #pragma unroll
      for (int c = 0; c < 8; c++) {
        bfrag b = *(const bfrag*)(Bs16 + (size_t)(c * 16 + fr) * 40 + ko);
        acc[r][c] = __builtin_amdgcn_mfma_f32_16x16x32_bf16(a, b, acc[r][c], 0, 0, 0);
      }
    }
    __syncthreads();
  }

  #pragma unroll
  for (int r = 0; r < 2; r++) {
    int rbase = m0 + wid * 32 + r * 16 + (lane >> 4) * 4;
    float ns[4];
    #pragma unroll
    for (int g = 0; g < 4; g++) ns[g] = (rbase + g < N) ? norm_src[rbase + g] : 0.f;
    #pragma unroll
    for (int c = 0; c < 8; c++) {
      int col = c * 16 + fr;
      #pragma unroll
      for (int g = 0; g < 4; g++) {
        int row = rbase + g;
        if (row < N) h1[(size_t)row * NF1 + col] = f2bf(acc[r][c][g] * ns[g]);
      }
    }
  }
}

// ---------------- fused gather1 + per-node GEMM2 (wave-per-node) ----------------
// Grid-stride persistent blocks: stage W2 (12.4 KB LDS) once, then each wave
// processes nodes independently: gather h1 rows -> epilogue -> park h2 row in
// LDS (64 uints) -> lanes 0..47 dot the row against W2 columns -> g (bf16).
#define W2STR 66   // uint stride per W2 row: (66f+kp)%32 -> max 3-way conflict
__global__ __launch_bounds__(256) void k_g1g2(const unsigned* __restrict__ off,
                                              const int* __restrict__ csr,
                                              const unsigned short* __restrict__ h1,
                                              const float* __restrict__ norm_dst,
                                              const float* __restrict__ norm_src,
                                              const float* __restrict__ b1,
                                              const unsigned* __restrict__ W2t32,
                                              unsigned short* __restrict__ g, int N) {
  __shared__ unsigned W2L[48 * W2STR];
  __shared__ unsigned row[4 * 64];
  const int t = threadIdx.x;
  const int lane = t & 63, wid = t >> 6;
  for (int i = t; i < 48 * 64; i += 256) {
    W2L[(i >> 6) * W2STR + (i & 63)] = W2t32[i];
  }
  __syncthreads();

  const int f = lane << 1;
  unsigned* rp = &row[wid * 64];
  const unsigned* wp = &W2L[lane * W2STR];
  const int ngroups = (N + 3) >> 2;

  for (int grp = blockIdx.x; grp < ngroups; grp += gridDim.x) {
    int node = grp * 4 + wid;
    if (node >= N) continue;
    unsigned j = off[node], e1 = off[node + 1];
    float ax = 0.f, ay = 0.f;
    for (; j + 4 <= e1; j += 4) {
      int s0 = csr[j], s1 = csr[j+1], s2 = csr[j+2], s3 = csr[j+3];
      unsigned v0 = *(const unsigned*)(h1 + (size_t)s0 * NF1 + f);
      unsigned v1 = *(const unsigned*)(h1 + (size_t)s1 * NF1 + f);
      unsigned v2 = *(const unsigned*)(h1 + (size_t)s2 * NF1 + f);
      unsigned v3 = *(const unsigned*)(h1 + (size_t)s3 * NF1 + f);
      ax += (bflo(v0) + bflo(v1)) + (bflo(v2) + bflo(v3));
      ay += (bfhi(v0) + bfhi(v1)) + (bfhi(v2) + bfhi(v3));
    }
    for (; j < e1; j++) {
      unsigned v = *(const unsigned*)(h1 + (size_t)csr[j] * NF1 + f);
      ax += bflo(v); ay += bfhi(v);
    }
    float nd = norm_dst[node], ns = norm_src[node];
    float2 bb = *(const float2*)(b1 + f);
    float v0 = fmaxf(ax * nd + bb.x, 0.f);
    float v1 = fmaxf(ay * nd + bb.y, 0.f);
    int jf = node * NF1 + f;
    v0 *= dropout_mul(jf) * ns;
    v1 *= dropout_mul(jf + 1) * ns;
    rp[lane] = pack2bf(v0, v1);
    __builtin_amdgcn_wave_barrier();   // order LDS write before cross-lane reads
    if (lane < 48) {
      float acc = 0.f;
      #pragma unroll
      for (int kp = 0; kp < 64; kp += 2) {
        uint2 u = *(const uint2*)(rp + kp);     // broadcast (same addr all lanes)
        uint2 w = *(const uint2*)(wp + kp);
        acc += bflo(u.x) * bflo(w.x) + bfhi(u.x) * bfhi(w.x)
             + bflo(u.y) * bflo(w.y) + bfhi(u.y) * bfhi(w.y);
      }
      g[(size_t)node * 48 + lane] = f2bf(acc);
    }
    __builtin_amdgcn_wave_barrier();   // keep next iter's row write after reads
  }
}

// ---------------- gather2 + bias + log_softmax -> out ----------------
__global__ __launch_bounds__(256) void k_gather2(const unsigned* __restrict__ off,
                                                 const int* __restrict__ csr,
                                                 const unsigned short* __restrict__ g,
                                                 const float* __restrict__ norm_dst,
                                                 const float* __restrict__ b2,
                                                 float* __restrict__ out, int N) {
  int node = (blockIdx.x * 256 + threadIdx.x) >> 6;
  int lane = threadIdx.x & 63;
  if (node >= N) return;
  unsigned j = off[node], e1 = off[node + 1];
  float acc = 0.f;
  for (; j + 4 <= e1; j += 4) {
    int s0 = csr[j], s1 = csr[j+1], s2 = csr[j+2], s3 = csr[j+3];
    if (lane < 48) {
      float a0 = bf2f(g[(size_t)s0 * 48 + lane]);
      float a1 = bf2f(g[(size_t)s1 * 48 + lane]);
      float a2 = bf2f(g[(size_t)s2 * 48 + lane]);
      float a3 = bf2f(g[(size_t)s3 * 48 + lane]);
      acc += (a0 + a1) + (a2 + a3);
    }
  }
  for (; j < e1; j++) {
    if (lane < 48) acc += bf2f(g[(size_t)csr[j] * 48 + lane]);
  }
  float nd = norm_dst[node];
  float vr = 0.f, m = -INFINITY;
  if (lane < NC) {
    vr = acc * nd + b2[lane];
    m = vr;
  }
  #pragma unroll
  for (int o = 32; o; o >>= 1) m = fmaxf(m, __shfl_xor(m, o));
  float ex = (lane < NC) ? expf(vr - m) : 0.f;
  #pragma unroll
  for (int o = 32; o; o >>= 1) ex += __shfl_xor(ex, o);
  float ls = logf(ex);
  if (lane < NC) out[(size_t)node * NC + lane] = vr - m - ls;
}

extern "C" void kernel_launch(void* const* d_in, const int* in_sizes, int n_in,
                              void* d_out, int out_size, void* d_ws, size_t ws_size,
                              hipStream_t stream) {
  const float* x  = (const float*)d_in[0];
  const int*   ei = (const int*)d_in[1];
  const float* W1 = (const float*)d_in[2];
  const float* b1 = (const float*)d_in[3];
  const float* W2 = (const float*)d_in[4];
  const float* b2 = (const float*)d_in[5];
  float* out = (float*)d_out;

  const int N = in_sizes[0] / NF0;   // 100000
  const int E = in_sizes[1] / 2;     // 1600000
  const int nbk = (N + CB - 1) / CB; // 98

  unsigned* ws = (unsigned*)d_ws;
  size_t o = 0;
  auto alloc = [&](size_t elems) { size_t p = o; o += (elems + 3) & ~(size_t)3; return p; };
  float*    norm_src = (float*)(ws + alloc(N));
  float*    norm_dst = (float*)(ws + alloc(N));
  unsigned* off      = ws + alloc(N + 1);
  unsigned* bCntD    = ws + alloc(128);   // bCntD,bCntS,curD,curS contiguous: one memset
  unsigned* bCntS    = ws + alloc(128);
  unsigned* curD     = ws + alloc(128);
  unsigned* curS     = ws + alloc(128);
  unsigned* pd       = ws + alloc(E);                        // 6.4 MB
  unsigned short* ps = (unsigned short*)(ws + alloc(E / 2)); // 3.2 MB
  int*      csr      = (int*)(ws + alloc(E));                // 6.4 MB
  unsigned* W1t32    = ws + alloc(128 * 128);
  unsigned* W2t32    = ws + alloc(48 * 64);
  unsigned short* h1 = (unsigned short*)(ws + alloc((size_t)N * NF1 / 2));
  // g (N*48 bf16) overlays pd+ps (dead after k_fine): E*3 ushorts available.
  unsigned short* gbuf;
  if ((size_t)E * 3 >= (size_t)N * 48) {
    gbuf = (unsigned short*)pd;
  } else {
    gbuf = (unsigned short*)(ws + alloc(((size_t)N * 48 + 1) / 2));
  }

  hipMemsetAsync(bCntD, 0, 512 * sizeof(unsigned), stream);

  int wblk = (128 * 128 + 48 * 64 + 255) / 256;
  k_chist<<<256 + wblk, 256, 0, stream>>>(ei, E, nbk, bCntD, bCntS, W1, W2, W1t32, W2t32);
  k_cscatter<<<256, 256, 0, stream>>>(ei, E, bCntD, bCntS, curD, curS, pd, ps, nbk);
  k_fine<<<2 * nbk, 256, 0, stream>>>(bCntD, bCntS, pd, ps, off, norm_dst, norm_src,
                                      csr, N, E, nbk);
  k_gemm1<<<(N + 127) / 128, 256, 0, stream>>>(x, W1t32, norm_src, h1, N);
  k_g1g2<<<2048, 256, 0, stream>>>(off, csr, h1, norm_dst, norm_src, b1,
                                   W2t32, gbuf, N);
  k_gather2<<<((size_t)N * 64 + 255) / 256, 256, 0, stream>>>(
      off, csr, gbuf, norm_dst, b2, out, N);
}